// Round 1
// baseline (507.044 us; speedup 1.0000x reference)
//
#include <hip/hip_runtime.h>

#define NS   16
#define NV   4
#define FEAT 48          // N_EDGE_FEAT
#define WN   320         // W_NUMEL
#define MSG  28          // 16 + 12 output features per edge
#define TE   32          // edges per block
#define LDW  324         // padded row stride (floats) for w tile: 324*4=1296 B, 16B aligned

__global__ __launch_bounds__(256, 3) void edge_kernel(
    const float* __restrict__ node_attr,
    const float* __restrict__ edge_attr,
    const float* __restrict__ edge_sh,
    const float* __restrict__ fc1_w,
    const float* __restrict__ fc1_b,
    const float* __restrict__ fc2_w,
    const float* __restrict__ fc2_b,
    const int*   __restrict__ edge_index,
    float* __restrict__ out_acc,   // [N][28], pre-zeroed
    float* __restrict__ cnt,       // [N], pre-zeroed
    int Etot)
{
    __shared__ float sW[TE * LDW];   // per-edge fc2 output tile
    __shared__ float sX[TE * 17];    // per-edge x = node_attr[dst] (padded)

    const int tid  = threadIdx.x;
    const int wave = tid >> 6;
    const int lane = tid & 63;
    const int e0   = blockIdx.x * TE + wave * 8;   // this wave's 8 edges

    // ---------- Phase A: lanes 0..47 load ea component `lane` for 8 edges ----------
    float ea[8];
    float h[8];
    #pragma unroll
    for (int i = 0; i < 8; ++i) { ea[i] = 0.f; h[i] = 0.f; }

    if (lane < FEAT) {
        #pragma unroll
        for (int i = 0; i < 8; ++i) {
            const int e = e0 + i;
            float v = 0.f;
            if (e < Etot) {
                if (lane < NS) {
                    v = edge_attr[e * NS + lane];
                } else if (lane < 2 * NS) {
                    const int s = edge_index[e];
                    v = node_attr[s * NS + (lane - NS)];
                } else {
                    const int d = edge_index[Etot + e];
                    v = node_attr[d * NS + (lane - 2 * NS)];
                }
            }
            ea[i] = v;
            if (lane >= 2 * NS) {
                // stash x = node_attr[dst] for the TP phase
                sX[(wave * 8 + i) * 17 + (lane - 2 * NS)] = v;
            }
        }

        // ---------- Phase B: fc1 -> h (lane = output column j) ----------
        float acc1[8];
        const float b1 = fc1_b[lane];
        #pragma unroll
        for (int i = 0; i < 8; ++i) acc1[i] = b1;

        #pragma unroll 4
        for (int k = 0; k < FEAT; ++k) {
            const float wv = fc1_w[k * FEAT + lane];
            #pragma unroll
            for (int i = 0; i < 8; ++i) {
                const float eav = __uint_as_float(
                    __builtin_amdgcn_readlane(__float_as_uint(ea[i]), k));
                acc1[i] = fmaf(eav, wv, acc1[i]);
            }
        }
        #pragma unroll
        for (int i = 0; i < 8; ++i) h[i] = fmaxf(acc1[i], 0.f);  // relu
    }

    // ---------- Phase C: fc2 (all 64 lanes; lane owns 4 w0 cols + 1 w1 col) ----------
    float4 accv[8];
    float  accs[8];
    {
        const float4 b2v = *reinterpret_cast<const float4*>(&fc2_b[lane * 4]);
        const float  b2s = fc2_b[256 + lane];
        #pragma unroll
        for (int i = 0; i < 8; ++i) { accv[i] = b2v; accs[i] = b2s; }
    }

    #pragma unroll 4
    for (int k = 0; k < FEAT; ++k) {
        const float4 wv = *reinterpret_cast<const float4*>(&fc2_w[k * WN + lane * 4]);
        const float  ws = fc2_w[k * WN + 256 + lane];
        #pragma unroll
        for (int i = 0; i < 8; ++i) {
            const float hk = __uint_as_float(
                __builtin_amdgcn_readlane(__float_as_uint(h[i]), k));
            accv[i].x = fmaf(hk, wv.x, accv[i].x);
            accv[i].y = fmaf(hk, wv.y, accv[i].y);
            accv[i].z = fmaf(hk, wv.z, accv[i].z);
            accv[i].w = fmaf(hk, wv.w, accv[i].w);
            accs[i]   = fmaf(hk, ws, accs[i]);
        }
    }

    // ---------- Phase D: stash w tile in LDS ----------
    #pragma unroll
    for (int i = 0; i < 8; ++i) {
        float* row = &sW[(wave * 8 + i) * LDW];
        *reinterpret_cast<float4*>(&row[lane * 4]) = accv[i];
        row[256 + lane] = accs[i];
    }
    __syncthreads();

    // ---------- Phase E: tensor product + scatter (8 threads per edge) ----------
    const int e_loc = tid >> 3;          // 0..31
    const int sub   = tid & 7;
    const int e     = blockIdx.x * TE + e_loc;
    if (e < Etot) {
        const int src = edge_index[e];
        const float* wrow = &sW[e_loc * LDW];
        const float* xrow = &sX[e_loc * 17];
        float x[NS];
        #pragma unroll
        for (int u = 0; u < NS; ++u) x[u] = xrow[u];

        const float sh0 = edge_sh[e * 9 + 0];
        // out0: columns c = sub, sub+8
        #pragma unroll
        for (int p = 0; p < 2; ++p) {
            const int c = sub + 8 * p;
            float s = 0.f;
            #pragma unroll
            for (int u = 0; u < NS; ++u) s = fmaf(x[u], wrow[u * NS + c], s);
            atomicAdd(&out_acc[src * MSG + c], 0.25f * sh0 * s);
        }
        // out1: v = sub (sub < 4), components m = 0..2
        if (sub < NV) {
            const int v = sub;
            float s = 0.f;
            #pragma unroll
            for (int u = 0; u < NS; ++u) s = fmaf(x[u], wrow[NS * NS + u * NV + v], s);
            s *= 0.25f;
            #pragma unroll
            for (int m = 0; m < 3; ++m) {
                const float shm = edge_sh[e * 9 + 1 + m];
                atomicAdd(&out_acc[src * MSG + NS + v * 3 + m], s * shm);
            }
        }
        if (sub == 7) atomicAdd(&cnt[src], 1.0f);
    }
}

__global__ void finalize_kernel(float* __restrict__ out,
                                const float* __restrict__ cnt, int total)
{
    const int idx = blockIdx.x * blockDim.x + threadIdx.x;
    if (idx < total) {
        const int n = idx / MSG;
        out[idx] = out[idx] / fmaxf(cnt[n], 1.0f);
    }
}

extern "C" void kernel_launch(void* const* d_in, const int* in_sizes, int n_in,
                              void* d_out, int out_size, void* d_ws, size_t ws_size,
                              hipStream_t stream)
{
    const float* node_attr  = (const float*)d_in[0];
    const float* edge_attr  = (const float*)d_in[1];
    const float* edge_sh    = (const float*)d_in[2];
    const float* fc1_w      = (const float*)d_in[3];
    const float* fc1_b      = (const float*)d_in[4];
    const float* fc2_w      = (const float*)d_in[5];
    const float* fc2_b      = (const float*)d_in[6];
    const int*   edge_index = (const int*)d_in[7];

    const int N = in_sizes[0] / NS;
    const int E = in_sizes[1] / NS;

    float* out = (float*)d_out;
    float* cntp = (float*)d_ws;

    hipMemsetAsync(d_out, 0, (size_t)out_size * sizeof(float), stream);
    hipMemsetAsync(d_ws, 0, (size_t)N * sizeof(float), stream);

    const int grid = (E + TE - 1) / TE;
    edge_kernel<<<grid, 256, 0, stream>>>(node_attr, edge_attr, edge_sh,
                                          fc1_w, fc1_b, fc2_w, fc2_b,
                                          edge_index, out, cntp, E);

    const int total = N * MSG;
    finalize_kernel<<<(total + 255) / 256, 256, 0, stream>>>(out, cntp, total);
}

// Round 2
// 177.819 us; speedup vs baseline: 2.8515x; 2.8515x over previous
//
#include <hip/hip_runtime.h>

#define NS   16
#define NV   4
#define FEAT 48          // N_EDGE_FEAT
#define WN   320         // W_NUMEL
#define MSG  28          // 16 + 12 output features per edge

typedef __bf16 bf16x8 __attribute__((ext_vector_type(8)));
typedef float  f32x4  __attribute__((ext_vector_type(4)));

#define PK_OFF    (256 * 1024)   // byte offset of packed weights inside d_ws
#define PK1_ELEMS (2 * 3 * 64 * 8)    // 3072 bf16
#define PK2_ELEMS (2 * 20 * 64 * 8)   // 20480 bf16

// Pack fc1_w / fc2_w into bf16 MFMA B-fragment layout:
// frag (ks, nt): lane l holds B[k = ks*32 + 8*(l>>4) + j][n = nt*16 + (l&15)], j=0..7
__global__ void pack_weights(const float* __restrict__ fc1_w,
                             const float* __restrict__ fc2_w,
                             __bf16* __restrict__ pk1,
                             __bf16* __restrict__ pk2)
{
    const int idx = blockIdx.x * blockDim.x + threadIdx.x;
    const int stride = gridDim.x * blockDim.x;
    for (int i = idx; i < PK1_ELEMS; i += stride) {
        const int j = i & 7, lane = (i >> 3) & 63, t = i >> 9;  // t = ks*3 + nt
        const int nt = t % 3, ks = t / 3;
        const int k = ks * 32 + 8 * (lane >> 4) + j;
        const int n = nt * 16 + (lane & 15);
        pk1[i] = (k < FEAT) ? (__bf16)fc1_w[k * FEAT + n] : (__bf16)0.f;
    }
    for (int i = idx; i < PK2_ELEMS; i += stride) {
        const int j = i & 7, lane = (i >> 3) & 63, t = i >> 9;  // t = ks*20 + nt
        const int nt = t % 20, ks = t / 20;
        const int k = ks * 32 + 8 * (lane >> 4) + j;
        const int n = nt * 16 + (lane & 15);
        pk2[i] = (k < FEAT) ? (__bf16)fc2_w[k * WN + n] : (__bf16)0.f;
    }
}

__global__ __launch_bounds__(256, 4) void edge_mfma_kernel(
    const float* __restrict__ node_attr,
    const float* __restrict__ edge_attr,
    const float* __restrict__ edge_sh,
    const float* __restrict__ fc1_b,
    const float* __restrict__ fc2_b,
    const int*   __restrict__ edge_index,
    const __bf16* __restrict__ pk1,
    const __bf16* __restrict__ pk2,
    float* __restrict__ out_acc,   // [N][28] pre-zeroed
    float* __restrict__ cnt,       // [N] pre-zeroed
    int E)
{
    // all LDS is wave-private (no cross-wave traffic, no __syncthreads)
    __shared__ __bf16 sH[4][16][56];    // h tile, row stride 112 B (16B-aligned)
    __shared__ float  sX[4][16][17];    // x = node_attr[dst], fp32
    __shared__ float  sSh[4][16][4];    // sh0..sh3 per edge
    __shared__ int    sSrc[4][16];      // src index per edge

    const int tid = threadIdx.x;
    const int w   = tid >> 6;
    const int l   = tid & 63;
    const int q   = l >> 4;         // k-block selector for A/B frags
    const int r16 = l & 15;
    const int e0  = blockIdx.x * 64 + w * 16;   // this wave's 16 edges
    const int e   = e0 + r16;
    const bool ev = (e < E);

    const float4 z4 = make_float4(0.f, 0.f, 0.f, 0.f);

    // ---------------- gather A fragments (ea, K padded 48->64) ----------------
    // kstep0: features 0..31  = edge_attr[0..15] | node_attr[src][0..15]
    bf16x8 a0;
    {
        float4 fa = z4, fb = z4;
        if (ev) {
            const float* p0 = (q < 2)
                ? (edge_attr + (size_t)e * NS + q * 8)
                : (node_attr + (size_t)edge_index[e] * NS + (q - 2) * 8);
            fa = reinterpret_cast<const float4*>(p0)[0];
            fb = reinterpret_cast<const float4*>(p0)[1];
        }
        a0[0] = (__bf16)fa.x; a0[1] = (__bf16)fa.y; a0[2] = (__bf16)fa.z; a0[3] = (__bf16)fa.w;
        a0[4] = (__bf16)fb.x; a0[5] = (__bf16)fb.y; a0[6] = (__bf16)fb.z; a0[7] = (__bf16)fb.w;
    }
    // kstep1: features 32..47 = node_attr[dst][0..15], 48..63 = zero pad
    bf16x8 a1;
    if (q < 2) {
        float4 ga = z4, gb = z4;
        if (ev) {
            const float* p1 = node_attr + (size_t)edge_index[E + e] * NS + q * 8;
            ga = reinterpret_cast<const float4*>(p1)[0];
            gb = reinterpret_cast<const float4*>(p1)[1];
        }
        a1[0] = (__bf16)ga.x; a1[1] = (__bf16)ga.y; a1[2] = (__bf16)ga.z; a1[3] = (__bf16)ga.w;
        a1[4] = (__bf16)gb.x; a1[5] = (__bf16)gb.y; a1[6] = (__bf16)gb.z; a1[7] = (__bf16)gb.w;
        float* xp = &sX[w][r16][q * 8];
        xp[0] = ga.x; xp[1] = ga.y; xp[2] = ga.z; xp[3] = ga.w;
        xp[4] = gb.x; xp[5] = gb.y; xp[6] = gb.z; xp[7] = gb.w;
    } else {
        #pragma unroll
        for (int j = 0; j < 8; ++j) a1[j] = (__bf16)0.f;
    }
    if (l < 16) {
        sSrc[w][l] = ev ? edge_index[e] : 0;
        #pragma unroll
        for (int mm = 0; mm < 4; ++mm)
            sSh[w][l][mm] = ev ? edge_sh[(size_t)e * 9 + mm] : 0.f;
    }

    // ---------------- fc1: (16x64) @ (64x48) -> h, relu, stash bf16 in LDS ----------------
    #pragma unroll
    for (int nt = 0; nt < 3; ++nt) {
        bf16x8 b0 = *reinterpret_cast<const bf16x8*>(pk1 + ((size_t)(0 * 3 + nt) * 64 + l) * 8);
        bf16x8 b1 = *reinterpret_cast<const bf16x8*>(pk1 + ((size_t)(1 * 3 + nt) * 64 + l) * 8);
        const float bias = fc1_b[nt * 16 + r16];
        f32x4 acc = {bias, bias, bias, bias};
        acc = __builtin_amdgcn_mfma_f32_16x16x32_bf16(a0, b0, acc, 0, 0, 0);
        acc = __builtin_amdgcn_mfma_f32_16x16x32_bf16(a1, b1, acc, 0, 0, 0);
        #pragma unroll
        for (int g = 0; g < 4; ++g) {
            const float hv = fmaxf(acc[g], 0.f);            // relu
            sH[w][4 * q + g][nt * 16 + r16] = (__bf16)hv;   // D: row=4q+g, col=16nt+r16
        }
    }

    // ---------------- h -> A fragments for fc2 ----------------
    bf16x8 ha0 = *reinterpret_cast<const bf16x8*>(&sH[w][r16][q * 8]);
    bf16x8 ha1;
    if (q < 2) {
        ha1 = *reinterpret_cast<const bf16x8*>(&sH[w][r16][32 + q * 8]);
    } else {
        #pragma unroll
        for (int j = 0; j < 8; ++j) ha1[j] = (__bf16)0.f;
    }

    // ---------------- fc2 + fused tensor product ----------------
    f32x4 acc0 = {0.f, 0.f, 0.f, 0.f};   // out0[e=4q+g][c=r16]
    f32x4 acc1 = {0.f, 0.f, 0.f, 0.f};   // partial w1 sums
    const int row = 4 * q;
    #pragma unroll 4
    for (int nt = 0; nt < 20; ++nt) {
        bf16x8 b0 = *reinterpret_cast<const bf16x8*>(pk2 + ((size_t)(0 * 20 + nt) * 64 + l) * 8);
        bf16x8 b1 = *reinterpret_cast<const bf16x8*>(pk2 + ((size_t)(1 * 20 + nt) * 64 + l) * 8);
        const float bias = fc2_b[nt * 16 + r16];
        f32x4 d = {bias, bias, bias, bias};
        d = __builtin_amdgcn_mfma_f32_16x16x32_bf16(ha0, b0, d, 0, 0, 0);
        d = __builtin_amdgcn_mfma_f32_16x16x32_bf16(ha1, b1, d, 0, 0, 0);
        if (nt < 16) {
            // wcol = nt*16 + r16 -> w0[u=nt][c=r16]
            #pragma unroll
            for (int g = 0; g < 4; ++g)
                acc0[g] = fmaf(sX[w][row + g][nt], d[g], acc0[g]);
        } else {
            // wcol-256 = (nt-16)*16 + r16 -> w1[u=(nt-16)*4+(r16>>2)][v=r16&3]
            const int u = (nt - 16) * 4 + (r16 >> 2);
            #pragma unroll
            for (int g = 0; g < 4; ++g)
                acc1[g] = fmaf(sX[w][row + g][u], d[g], acc1[g]);
        }
    }

    const float inv = 0.25f;   // 1/sqrt(16)

    // out0 scatter: 16 atomics per edge
    #pragma unroll
    for (int g = 0; g < 4; ++g) {
        const int rr = row + g;
        if (e0 + rr < E) {
            const float v = inv * sSh[w][rr][0] * acc0[g];
            atomicAdd(&out_acc[(size_t)sSrc[w][rr] * MSG + r16], v);
        }
    }

    // out1: reduce partial u-sums across lane groups (bits 2,3 of lane)
    #pragma unroll
    for (int g = 0; g < 4; ++g) {
        float s = acc1[g];
        s += __shfl_xor(s, 4);
        s += __shfl_xor(s, 8);
        acc1[g] = s;
    }
    const int mcomp = r16 >> 2;       // 0..3; 3 is idle
    const int vidx  = l & 3;
    if (mcomp < 3) {
        #pragma unroll
        for (int g = 0; g < 4; ++g) {
            const int rr = row + g;
            if (e0 + rr < E) {
                const float val = inv * acc1[g] * sSh[w][rr][1 + mcomp];
                atomicAdd(&out_acc[(size_t)sSrc[w][rr] * MSG + NS + vidx * 3 + mcomp], val);
            }
        }
    }
    if (r16 == 0) {
        #pragma unroll
        for (int g = 0; g < 4; ++g) {
            const int rr = row + g;
            if (e0 + rr < E) atomicAdd(&cnt[sSrc[w][rr]], 1.f);
        }
    }
}

__global__ void finalize_kernel(float* __restrict__ out,
                                const float* __restrict__ cnt, int total)
{
    const int idx = blockIdx.x * blockDim.x + threadIdx.x;
    if (idx < total) {
        const int n = idx / MSG;
        out[idx] = out[idx] / fmaxf(cnt[n], 1.0f);
    }
}

extern "C" void kernel_launch(void* const* d_in, const int* in_sizes, int n_in,
                              void* d_out, int out_size, void* d_ws, size_t ws_size,
                              hipStream_t stream)
{
    const float* node_attr  = (const float*)d_in[0];
    const float* edge_attr  = (const float*)d_in[1];
    const float* edge_sh    = (const float*)d_in[2];
    const float* fc1_w      = (const float*)d_in[3];
    const float* fc1_b      = (const float*)d_in[4];
    const float* fc2_w      = (const float*)d_in[5];
    const float* fc2_b      = (const float*)d_in[6];
    const int*   edge_index = (const int*)d_in[7];

    const int N = in_sizes[0] / NS;
    const int E = in_sizes[1] / NS;

    float*  out = (float*)d_out;
    float*  cntp = (float*)d_ws;
    __bf16* pk1 = (__bf16*)((char*)d_ws + PK_OFF);
    __bf16* pk2 = (__bf16*)((char*)d_ws + PK_OFF + 8192);

    hipMemsetAsync(d_out, 0, (size_t)out_size * sizeof(float), stream);
    hipMemsetAsync(d_ws, 0, (size_t)N * sizeof(float), stream);

    pack_weights<<<40, 256, 0, stream>>>(fc1_w, fc2_w, pk1, pk2);

    const int grid = (E + 63) / 64;
    edge_mfma_kernel<<<grid, 256, 0, stream>>>(node_attr, edge_attr, edge_sh,
                                               fc1_b, fc2_b, edge_index,
                                               pk1, pk2, out, cntp, E);

    const int total = N * MSG;
    finalize_kernel<<<(total + 255) / 256, 256, 0, stream>>>(out, cntp, total);
}